// Round 13
// baseline (99.443 us; speedup 1.0000x reference)
//
#include <hip/hip_runtime.h>
#include <hip/hip_bf16.h>

// B=8, N=256, D=128, H=256, K=128
// 3-kernel split: A (hi/hjbT precompute) -> B (v = mul*x+bias, barrier-free)
//                 -> C (pure streaming RBF, proven 45.7us)

#define NB 8
#define NN 256
#define ND 128
#define NH 256
#define NK 128

typedef float f32x4 __attribute__((ext_vector_type(4)));
typedef float f32x2 __attribute__((ext_vector_type(2)));

// ---------------- Kernel A: hi[bi][h] and hjbT[b][h][j] = hj + b1 ----------------
__global__ __launch_bounds__(256) void precompute_hij(
    const float* __restrict__ atom, const float* __restrict__ W1,
    const float* __restrict__ b1,
    float* __restrict__ hi, float* __restrict__ hjbT) {
  const int h = threadIdx.x;
  const int base = blockIdx.x * 8;
  const int b  = base >> 8;
  const int j0 = base & 255;
  __shared__ float a[8][ND];
  for (int t = threadIdx.x; t < 8 * ND; t += 256) {
    a[t >> 7][t & 127] = atom[(size_t)base * ND + t];
  }
  __syncthreads();
  float acc0[8], acc1[8];
  const float bv = b1[h];
#pragma unroll
  for (int r = 0; r < 8; ++r) { acc0[r] = 0.f; acc1[r] = bv; }
  for (int d = 0; d < ND; ++d) {
    const float w0 = W1[d * NH + h];
    const float w1 = W1[(ND + d) * NH + h];
#pragma unroll
    for (int r = 0; r < 8; ++r) {
      acc0[r] = fmaf(a[r][d], w0, acc0[r]);
      acc1[r] = fmaf(a[r][d], w1, acc1[r]);
    }
  }
#pragma unroll
  for (int r = 0; r < 8; ++r) {
    hi[(size_t)(base + r) * NH + h] = acc0[r];
    hjbT[((size_t)b * NH + h) * NN + (j0 + r)] = acc1[r];
  }
}

// ---------------- Kernel B: barrier-free v compute ----------------
// grid = B*N/2 = 1024 blocks, 256 thr (4 waves); b = blockIdx&7 (XCD locality).
// Wave wv: row = i0 + (wv>>1), j-half = wv&1. Lane l: j = j0 + 2l (float2).
// Full H=256 reduction per thread in registers; hi/W2 via s_loads; no LDS.
// 4 blocks/CU -> 16 waves/CU for latency hiding.
__global__ __launch_bounds__(256) void compute_v(
    const float* __restrict__ x,
    const float* __restrict__ hi, const float* __restrict__ hjbT,
    const float* __restrict__ W2, const float* __restrict__ b2,
    float* __restrict__ v) {
  const int b    = blockIdx.x & 7;
  const int i0   = (blockIdx.x >> 3) * 2;
  const int lane = threadIdx.x & 63;
  const int wv   = __builtin_amdgcn_readfirstlane((int)(threadIdx.x >> 6)); // SGPR
  const int row  = i0 + (wv >> 1);
  const int j0   = (wv & 1) * 128;
  const int bi   = b * NN + row;

  const float* __restrict__ hjp = hjbT + (size_t)b * NH * NN + j0 + 2 * lane;
  const float* __restrict__ hirow = hi + (size_t)bi * NH;  // uniform -> s_loads

  float s0a = 0.f, s1a = 0.f, s0b = 0.f, s1b = 0.f;
#pragma unroll 8
  for (int h = 0; h < NH; ++h) {
    const f32x2 hj = *reinterpret_cast<const f32x2*>(hjp + (size_t)h * NN);
    const float hih = hirow[h];        // s_load (uniform addr)
    const float w0  = W2[2 * h];       // s_load
    const float w1  = W2[2 * h + 1];
    const float a0 = fmaxf(hih + hj.x, 0.f);
    const float a1 = fmaxf(hih + hj.y, 0.f);
    s0a = fmaf(a0, w0, s0a); s1a = fmaf(a0, w1, s1a);
    s0b = fmaf(a1, w0, s0b); s1b = fmaf(a1, w1, s1b);
  }

  const float scale = 0.0625f;  // 1/sqrt(2*128)
  const float b20 = b2[0], b21 = b2[1];
  const f32x2 xv = *reinterpret_cast<const f32x2*>(x + (size_t)bi * NN + j0 + 2 * lane);
  f32x2 vv;
  vv.x = fmaf((s0a + b20) * scale, xv.x, (s1a + b21) * scale);
  vv.y = fmaf((s0b + b20) * scale, xv.y, (s1b + b21) * scale);
  *reinterpret_cast<f32x2*>(v + (size_t)bi * NN + j0 + 2 * lane) = vv;
}

// ---------------- Kernel C: pure streaming RBF (proven 45.7us) ----------------
__global__ __launch_bounds__(256) void rbf_store(
    const float* __restrict__ v,
    const float* __restrict__ means, const float* __restrict__ temps,
    float* __restrict__ out) {
  const int idx = blockIdx.x * 256 + threadIdx.x;
  const int k0  = (idx & 31) * 4;

  const float LOG2E = 1.44269504088896340736f;
  const float4 mv = *reinterpret_cast<const float4*>(means + k0);
  float4 tv = *reinterpret_cast<const float4*>(temps + k0);
  const float t0 = -fabsf(tv.x) * LOG2E;
  const float t1 = -fabsf(tv.y) * LOG2E;
  const float t2 = -fabsf(tv.z) * LOG2E;
  const float t3 = -fabsf(tv.w) * LOG2E;

  const float* __restrict__ vp = v + (idx >> 5);
  float* __restrict__ op = out + (size_t)idx * 4;

#pragma unroll 4
  for (int s = 0; s < 32; ++s) {
    const float vj = vp[s * 16384];
    const float d0 = vj - mv.x;
    const float d1 = vj - mv.y;
    const float d2 = vj - mv.z;
    const float d3 = vj - mv.w;
    f32x4 e;
    e.x = __builtin_amdgcn_exp2f(d0 * d0 * t0);
    e.y = __builtin_amdgcn_exp2f(d1 * d1 * t1);
    e.z = __builtin_amdgcn_exp2f(d2 * d2 * t2);
    e.w = __builtin_amdgcn_exp2f(d3 * d3 * t3);
    *reinterpret_cast<f32x4*>(op + (size_t)s * 2097152) = e;
  }
}

extern "C" void kernel_launch(void* const* d_in, const int* in_sizes, int n_in,
                              void* d_out, int out_size, void* d_ws, size_t ws_size,
                              hipStream_t stream) {
  const float* x     = (const float*)d_in[0];
  const float* atom  = (const float*)d_in[1];
  const float* W1    = (const float*)d_in[2];
  const float* b1    = (const float*)d_in[3];
  const float* W2    = (const float*)d_in[4];
  const float* b2    = (const float*)d_in[5];
  const float* means = (const float*)d_in[6];
  const float* temps = (const float*)d_in[7];
  float* out = (float*)d_out;

  float* hi   = (float*)d_ws;                        // 2 MB: [B*N][H]
  float* hjbT = hi + (size_t)NB * NN * NH;           // 2 MB: [B][H][N]
  float* v    = hjbT + (size_t)NB * NH * NN;         // 2 MB: [B*N*N]

  precompute_hij<<<NB * NN / 8, 256, 0, stream>>>(atom, W1, b1, hi, hjbT);
  compute_v<<<NB * NN / 2, 256, 0, stream>>>(x, hi, hjbT, W2, b2, v);
  rbf_store<<<2048, 256, 0, stream>>>(v, means, temps, out);
}